// Round 12
// baseline (127.744 us; speedup 1.0000x reference)
//
#include <hip/hip_runtime.h>
#include <cmath>

#define NN 2048

#define EPSF 0.1f
#define K2 14.426950408889634f   /* (1/eps) * log2(e) */
#define LN2F 0.6931471805599453f

// ws layout (floats)
#define U_OFF   0
#define V_OFF   2048
#define ERR_OFF 4096
#define FLG_OFF 4112
#define DU_OFF  4128
#define CT_OFF  6176              // 2048*2048 transposed cost matrix

__device__ __forceinline__ float fexp2(float x) { return __builtin_amdgcn_exp2f(x); }
__device__ __forceinline__ float flog2(float x) { return __builtin_amdgcn_logf(x); }

// ---------------------------------------------------------------------------
// Kernel 1: C[i][j] = |x_i|^2 + |y_j|^2 - 2 x_i.y_j  (dot-product form).
// Writes Cout (misaligned d_out, scalar stores) and CT (aligned ws, float4
// stores via LDS transpose). Zero-inits ws + cost. grid (32,16), block 256.
// ---------------------------------------------------------------------------
__global__ __launch_bounds__(256) void sink_cost(
        const float* __restrict__ x, const float* __restrict__ y,
        float* __restrict__ Cout, float* __restrict__ CT,
        float* __restrict__ wsz, float* __restrict__ cost) {
    __shared__ float xs[128][65];
    __shared__ float ys[64][65];
    __shared__ float xn[128], yn[64];
    int tid = threadIdx.x;
    int bj = blockIdx.x, bi = blockIdx.y;

    if (bi == 0 && bj == 0) {
        // u(2048)+v(2048)+err(16)+flag(16)+du(2048) = 6176
        for (int k = tid; k < 6176; k += 256) wsz[k] = 0.f;
        if (tid == 0) cost[0] = 0.f;
    }

    const float4* x4 = (const float4*)x;
    const float4* y4 = (const float4*)y;
    for (int q = tid; q < 128 * 16; q += 256) {
        int r = q >> 4, dq = q & 15;
        float4 val = x4[(size_t)(bi * 128 + r) * 16 + dq];
        xs[r][dq * 4 + 0] = val.x; xs[r][dq * 4 + 1] = val.y;
        xs[r][dq * 4 + 2] = val.z; xs[r][dq * 4 + 3] = val.w;
    }
    for (int q = tid; q < 64 * 16; q += 256) {
        int r = q >> 4, dq = q & 15;
        float4 val = y4[(size_t)(bj * 64 + r) * 16 + dq];
        ys[r][dq * 4 + 0] = val.x; ys[r][dq * 4 + 1] = val.y;
        ys[r][dq * 4 + 2] = val.z; ys[r][dq * 4 + 3] = val.w;
    }
    __syncthreads();

    // cooperative row norms
    if (tid < 128) {
        float s = 0.f;
#pragma unroll 8
        for (int d = 0; d < 64; ++d) s = fmaf(xs[tid][d], xs[tid][d], s);
        xn[tid] = s;
    } else if (tid < 192) {
        int r = tid - 128;
        float s = 0.f;
#pragma unroll 8
        for (int d = 0; d < 64; ++d) s = fmaf(ys[r][d], ys[r][d], s);
        yn[r] = s;
    }
    __syncthreads();

    int tx = tid & 15, ty = tid >> 4;
    float acc[8][4];
#pragma unroll
    for (int ii = 0; ii < 8; ++ii)
#pragma unroll
        for (int jj = 0; jj < 4; ++jj) acc[ii][jj] = 0.f;

#pragma unroll 4
    for (int dd = 0; dd < 64; ++dd) {
        float xv[8], yv[4];
#pragma unroll
        for (int ii = 0; ii < 8; ++ii) xv[ii] = xs[ty + 16 * ii][dd];
#pragma unroll
        for (int jj = 0; jj < 4; ++jj) yv[jj] = ys[tx + 16 * jj][dd];
#pragma unroll
        for (int ii = 0; ii < 8; ++ii)
#pragma unroll
            for (int jj = 0; jj < 4; ++jj)
                acc[ii][jj] = fmaf(xv[ii], yv[jj], acc[ii][jj]);
    }

    float xnr[8], ynr[4];
#pragma unroll
    for (int ii = 0; ii < 8; ++ii) xnr[ii] = xn[ty + 16 * ii];
#pragma unroll
    for (int jj = 0; jj < 4; ++jj) ynr[jj] = yn[tx + 16 * jj];
    __syncthreads();   // all compute reads of xs/ys done before overwrite
#pragma unroll
    for (int ii = 0; ii < 8; ++ii)
#pragma unroll
        for (int jj = 0; jj < 4; ++jj) {
            int ri = ty + 16 * ii;
            int cj = tx + 16 * jj;
            float c = fmaf(-2.f, acc[ii][jj], xnr[ii] + ynr[jj]);
            Cout[(size_t)(bi * 128 + ri) * NN + bj * 64 + cj] = c;
            xs[ri][cj] = c;
        }
    __syncthreads();

    int c = tid >> 2, rb = (tid & 3) * 32;
    float4* dst = (float4*)(CT + (size_t)(bj * 64 + c) * NN + bi * 128 + rb);
#pragma unroll
    for (int k = 0; k < 8; ++k) {
        dst[k] = make_float4(xs[rb + 4 * k + 0][c], xs[rb + 4 * k + 1][c],
                             xs[rb + 4 * k + 2][c], xs[rb + 4 * k + 3][c]);
    }
}

// ---------------------------------------------------------------------------
// Kernel 2 (per iter, u half). grid 1024, block 256 (4 blocks/CU).
// Loads issued BEFORE the gate check so gate latency overlaps VMEM.
// ---------------------------------------------------------------------------
__global__ __launch_bounds__(256, 4) void sink_u(
        const float* __restrict__ C, float* __restrict__ u,
        const float* __restrict__ v, float* __restrict__ du,
        const float* __restrict__ err, float* __restrict__ flag,
        int it, float log_mu) {
    int tid = threadIdx.x;
    int r0 = blockIdx.x * 2;
    int w = tid >> 6, l = tid & 63;

    // issue data loads unconditionally (always-valid addresses)
    float4 va = *(const float4*)(v + 4 * tid);
    float4 vb = *(const float4*)(v + 1024 + 4 * tid);
    float c0[8], c1[8];
    {
        const float* row0 = C + (size_t)r0 * NN + 4 * tid;
        const float* row1 = row0 + NN;
#pragma unroll
        for (int g = 0; g < 4; ++g) { c0[g] = row0[g]; c0[g + 4] = row0[1024 + g]; }
#pragma unroll
        for (int g = 0; g < 4; ++g) { c1[g] = row1[g]; c1[g + 4] = row1[1024 + g]; }
    }

    // gate (scalar loads overlap the vector loads above)
    if (it > 0) {
        if (flag[it - 1] != 0.f || err[it - 1] < 0.1f) {
            if (blockIdx.x == 0 && tid == 0) flag[it] = 1.f;
            return;
        }
    }

    float vK[8] = { va.x * K2, va.y * K2, va.z * K2, va.w * K2,
                    vb.x * K2, vb.y * K2, vb.z * K2, vb.w * K2 };
    float a[2][8];
#pragma unroll
    for (int g = 0; g < 8; ++g) {
        a[0][g] = fmaf(-K2, c0[g], vK[g]);
        a[1][g] = fmaf(-K2, c1[g], vK[g]);
    }

    float m2[2];
#pragma unroll
    for (int r = 0; r < 2; ++r) {
        float q0 = fmaxf(fmaxf(a[r][0], a[r][1]), fmaxf(a[r][2], a[r][3]));
        float q1 = fmaxf(fmaxf(a[r][4], a[r][5]), fmaxf(a[r][6], a[r][7]));
        m2[r] = fmaxf(q0, q1);
    }
#pragma unroll
    for (int off = 1; off < 64; off <<= 1)
#pragma unroll
        for (int r = 0; r < 2; ++r)
            m2[r] = fmaxf(m2[r], __shfl_xor(m2[r], off));
    __shared__ float wsm[4][2], wss[4][2];
    if (l == 0)
#pragma unroll
        for (int r = 0; r < 2; ++r) wsm[w][r] = m2[r];
    __syncthreads();
    float M2[2];
#pragma unroll
    for (int r = 0; r < 2; ++r)
        M2[r] = fmaxf(fmaxf(wsm[0][r], wsm[1][r]), fmaxf(wsm[2][r], wsm[3][r]));

    float s2[2];
#pragma unroll
    for (int r = 0; r < 2; ++r) {
        float t0 = fexp2(a[r][0] - M2[r]) + fexp2(a[r][1] - M2[r]);
        float t1 = fexp2(a[r][2] - M2[r]) + fexp2(a[r][3] - M2[r]);
        float t2 = fexp2(a[r][4] - M2[r]) + fexp2(a[r][5] - M2[r]);
        float t3 = fexp2(a[r][6] - M2[r]) + fexp2(a[r][7] - M2[r]);
        s2[r] = (t0 + t1) + (t2 + t3);
    }
#pragma unroll
    for (int off = 1; off < 64; off <<= 1)
#pragma unroll
        for (int r = 0; r < 2; ++r)
            s2[r] += __shfl_xor(s2[r], off);
    if (l == 0)
#pragma unroll
        for (int r = 0; r < 2; ++r) wss[w][r] = s2[r];
    __syncthreads();
    if (tid < 2) {
        float S = (wss[0][tid] + wss[1][tid]) + (wss[2][tid] + wss[3][tid]);
        float un = EPSF * (log_mu - LN2F * (M2[tid] + flog2(S)));
        du[r0 + tid] = fabsf(un - u[r0 + tid]);
        u[r0 + tid] = un;
    }
    if (blockIdx.x == 0 && tid == 0) flag[it] = 0.f;
}

// ---------------------------------------------------------------------------
// Kernel 3 (per iter, v half). grid 1024, block 256. Loads before gate.
// Block 0 reduces du -> err[it].
// ---------------------------------------------------------------------------
__global__ __launch_bounds__(256, 4) void sink_v(
        const float* __restrict__ CT, float* __restrict__ v,
        const float* __restrict__ u, const float* __restrict__ du,
        float* __restrict__ err, const float* __restrict__ flag,
        int it, float log_nu) {
    int tid = threadIdx.x;
    int j0 = blockIdx.x * 2;
    int w = tid >> 6, l = tid & 63;

    float4 ua = *(const float4*)(u + 4 * tid);
    float4 ub = *(const float4*)(u + 1024 + 4 * tid);
    float4 r0a, r0b, r1a, r1b;
    {
        const float* row0 = CT + (size_t)j0 * NN;
        const float* row1 = row0 + NN;
        r0a = *(const float4*)(row0 + 4 * tid);
        r0b = *(const float4*)(row0 + 1024 + 4 * tid);
        r1a = *(const float4*)(row1 + 4 * tid);
        r1b = *(const float4*)(row1 + 1024 + 4 * tid);
    }

    if (flag[it] != 0.f) return;

    float uK[8] = { ua.x * K2, ua.y * K2, ua.z * K2, ua.w * K2,
                    ub.x * K2, ub.y * K2, ub.z * K2, ub.w * K2 };
    float a[2][8];
    a[0][0] = fmaf(-K2, r0a.x, uK[0]); a[0][1] = fmaf(-K2, r0a.y, uK[1]);
    a[0][2] = fmaf(-K2, r0a.z, uK[2]); a[0][3] = fmaf(-K2, r0a.w, uK[3]);
    a[0][4] = fmaf(-K2, r0b.x, uK[4]); a[0][5] = fmaf(-K2, r0b.y, uK[5]);
    a[0][6] = fmaf(-K2, r0b.z, uK[6]); a[0][7] = fmaf(-K2, r0b.w, uK[7]);
    a[1][0] = fmaf(-K2, r1a.x, uK[0]); a[1][1] = fmaf(-K2, r1a.y, uK[1]);
    a[1][2] = fmaf(-K2, r1a.z, uK[2]); a[1][3] = fmaf(-K2, r1a.w, uK[3]);
    a[1][4] = fmaf(-K2, r1b.x, uK[4]); a[1][5] = fmaf(-K2, r1b.y, uK[5]);
    a[1][6] = fmaf(-K2, r1b.z, uK[6]); a[1][7] = fmaf(-K2, r1b.w, uK[7]);

    float m2[2];
#pragma unroll
    for (int r = 0; r < 2; ++r) {
        float q0 = fmaxf(fmaxf(a[r][0], a[r][1]), fmaxf(a[r][2], a[r][3]));
        float q1 = fmaxf(fmaxf(a[r][4], a[r][5]), fmaxf(a[r][6], a[r][7]));
        m2[r] = fmaxf(q0, q1);
    }
#pragma unroll
    for (int off = 1; off < 64; off <<= 1)
#pragma unroll
        for (int r = 0; r < 2; ++r)
            m2[r] = fmaxf(m2[r], __shfl_xor(m2[r], off));
    __shared__ float wsm[4][2], wss[4][2];
    if (l == 0)
#pragma unroll
        for (int r = 0; r < 2; ++r) wsm[w][r] = m2[r];
    __syncthreads();
    float M2[2];
#pragma unroll
    for (int r = 0; r < 2; ++r)
        M2[r] = fmaxf(fmaxf(wsm[0][r], wsm[1][r]), fmaxf(wsm[2][r], wsm[3][r]));

    float s2[2];
#pragma unroll
    for (int r = 0; r < 2; ++r) {
        float t0 = fexp2(a[r][0] - M2[r]) + fexp2(a[r][1] - M2[r]);
        float t1 = fexp2(a[r][2] - M2[r]) + fexp2(a[r][3] - M2[r]);
        float t2 = fexp2(a[r][4] - M2[r]) + fexp2(a[r][5] - M2[r]);
        float t3 = fexp2(a[r][6] - M2[r]) + fexp2(a[r][7] - M2[r]);
        s2[r] = (t0 + t1) + (t2 + t3);
    }
#pragma unroll
    for (int off = 1; off < 64; off <<= 1)
#pragma unroll
        for (int r = 0; r < 2; ++r)
            s2[r] += __shfl_xor(s2[r], off);
    if (l == 0)
#pragma unroll
        for (int r = 0; r < 2; ++r) wss[w][r] = s2[r];
    __syncthreads();
    if (tid < 2) {
        float S = (wss[0][tid] + wss[1][tid]) + (wss[2][tid] + wss[3][tid]);
        v[j0 + tid] = EPSF * (log_nu - LN2F * (M2[tid] + flog2(S)));
    }

    if (blockIdx.x == 0) {
        float t = 0.f;
#pragma unroll
        for (int k = 0; k < 8; ++k) t += du[tid + 256 * k];
#pragma unroll
        for (int off = 1; off < 64; off <<= 1) t += __shfl_xor(t, off);
        __shared__ float sl[4];
        if (l == 0) sl[w] = t;
        __syncthreads();
        if (tid == 0) err[it] = (sl[0] + sl[1]) + (sl[2] + sl[3]);
    }
}

// ---------------------------------------------------------------------------
// Kernel 4: pi = exp((-C+u+v)/eps), cost = sum(pi*C)
// grid 1024 (2 rows per block), block 256 (4 blocks/CU). Scalar C reads.
// ---------------------------------------------------------------------------
__global__ __launch_bounds__(256, 4) void sink_pi(
        const float* __restrict__ C, const float* __restrict__ u,
        const float* __restrict__ v, float* __restrict__ pi,
        float* __restrict__ cost) {
    int tid = threadIdx.x;
    const float4* v4 = (const float4*)v;
    float local = 0.f;
    for (int rr = 0; rr < 2; ++rr) {
        int i = blockIdx.x * 2 + rr;
        float ui = u[i];
        const float* row = C + (size_t)i * NN;
        float* prow = pi + (size_t)i * NN;
        for (int k = tid; k < NN / 4; k += 256) {
            float c0 = row[4 * k + 0], c1 = row[4 * k + 1];
            float c2 = row[4 * k + 2], c3 = row[4 * k + 3];
            float4 vv = v4[k];
            float p0 = fexp2((ui + vv.x - c0) * K2);
            float p1 = fexp2((ui + vv.y - c1) * K2);
            float p2 = fexp2((ui + vv.z - c2) * K2);
            float p3 = fexp2((ui + vv.w - c3) * K2);
            prow[4 * k + 0] = p0;
            prow[4 * k + 1] = p1;
            prow[4 * k + 2] = p2;
            prow[4 * k + 3] = p3;
            local = fmaf(p0, c0, local);
            local = fmaf(p1, c1, local);
            local = fmaf(p2, c2, local);
            local = fmaf(p3, c3, local);
        }
    }
#pragma unroll
    for (int off = 1; off < 64; off <<= 1) local += __shfl_xor(local, off);
    __shared__ float sl[4];
    if ((tid & 63) == 0) sl[tid >> 6] = local;
    __syncthreads();
    if (tid == 0) atomicAdd(cost, sl[0] + sl[1] + sl[2] + sl[3]);
}

extern "C" void kernel_launch(void* const* d_in, const int* in_sizes, int n_in,
                              void* d_out, int out_size, void* d_ws, size_t ws_size,
                              hipStream_t stream) {
    const float* x = (const float*)d_in[0];
    const float* y = (const float*)d_in[1];
    float* out  = (float*)d_out;
    float* cost = out;                       // [0]
    float* pi   = out + 1;                   // [1 .. 1+2048*2048)
    float* Cout = out + 1 + (size_t)NN * NN; // [.. 1+2*2048*2048)

    float* ws   = (float*)d_ws;
    float* u    = ws + U_OFF;
    float* v    = ws + V_OFF;
    float* err  = ws + ERR_OFF;
    float* flag = ws + FLG_OFF;
    float* du   = ws + DU_OFF;
    float* CT   = ws + CT_OFF;

    float log_mu = (float)log(1.0 / 2048.0 + 1e-8); // n == m -> log_nu == log_mu

    sink_cost<<<dim3(32, 16), 256, 0, stream>>>(x, y, Cout, CT, ws, cost);
    for (int it = 0; it < 10; ++it) {
        sink_u<<<1024, 256, 0, stream>>>(Cout, u, v, du, err, flag, it, log_mu);
        sink_v<<<1024, 256, 0, stream>>>(CT, v, u, du, err, flag, it, log_mu);
    }
    sink_pi<<<1024, 256, 0, stream>>>(Cout, u, v, pi, cost);
}